// Round 13
// baseline (351.685 us; speedup 1.0000x reference)
//
#include <hip/hip_runtime.h>
#include <hip/hip_bf16.h>
#include <math.h>

#define EPSV 1e-5f

typedef short bf16x8 __attribute__((ext_vector_type(8)));
typedef float f32x16 __attribute__((ext_vector_type(16)));
typedef unsigned int uint4v __attribute__((ext_vector_type(4)));

__device__ __forceinline__ float silu_f(float v) { return v / (1.0f + __expf(-v)); }

__device__ __forceinline__ unsigned short f2bf(float f) {
  __hip_bfloat16 h = __float2bfloat16(f);
  return __builtin_bit_cast(unsigned short, h);
}

// hardware 2^x (VOP1 v_exp_f32)
__device__ __forceinline__ float fexp2(float x) {
  float r;
  asm("v_exp_f32 %0, %1" : "=v"(r) : "v"(x));
  return r;
}

// packed f32x2 -> bf16x2 (low = lo, high = hi)
__device__ __forceinline__ unsigned int cvtpk(float lo, float hi) {
  unsigned int r;
  asm("v_cvt_pk_bf16_f32 %0, %1, %2" : "=v"(r) : "v"(lo), "v"(hi));
  return r;
}

__device__ __forceinline__ float bfu_lo(unsigned int w) {
  return __builtin_bit_cast(float, w << 16);
}
__device__ __forceinline__ float bfu_hi(unsigned int w) {
  return __builtin_bit_cast(float, w & 0xffff0000u);
}

__device__ __forceinline__ bf16x8 ld_frag(const unsigned short* p) {
  return *reinterpret_cast<const bf16x8*>(p);
}

__device__ __forceinline__ void gload16(const unsigned short* g, unsigned short* l) {
  __builtin_amdgcn_global_load_lds((const __attribute__((address_space(1))) void*)g,
                                   (__attribute__((address_space(3))) void*)l, 16, 0, 0);
}

// ---------------- 4x4 average pool: x[8,256,128,128] -> xkv[8,256,32,32] ----------------
__global__ __launch_bounds__(256) void pool_kernel(const float* __restrict__ x,
                                                   float* __restrict__ xkv) {
  int idx = blockIdx.x * 256 + threadIdx.x;
  int m = idx & 1023, bc = idx >> 10;
  int hh = m >> 5, ww = m & 31;
  const float* base = x + ((size_t)bc << 14) + (size_t)(hh * 4) * 128 + ww * 4;
  float s = 0.f;
#pragma unroll
  for (int i = 0; i < 4; ++i) {
    float4 v = *reinterpret_cast<const float4*>(base + i * 128);
    s += v.x + v.y + v.z + v.w;
  }
  xkv[idx] = s * 0.0625f;
}

// ---------------- cvt+transpose: x fp32 [b][c][n] -> xbfT bf16 [b][n][c] ----------------
__global__ __launch_bounds__(256) void cvtT_kernel(const float* __restrict__ x,
                                                   unsigned short* __restrict__ xbfT) {
  __shared__ unsigned short sT[64 * 68];
  const int tid = threadIdx.x;
  const int b = blockIdx.z, c0 = blockIdx.y * 64, n0 = blockIdx.x * 64;
  const float* xs = x + ((size_t)(b * 256 + c0) << 14) + n0;
#pragma unroll
  for (int pass = 0; pass < 4; ++pass) {
    int cc = (tid >> 4) + pass * 16;
    int col = (tid & 15) * 4;
    float4 v = *reinterpret_cast<const float4*>(xs + ((size_t)cc << 14) + col);
    unsigned short* d = &sT[cc * 68 + col];
    d[0] = f2bf(v.x); d[1] = f2bf(v.y); d[2] = f2bf(v.z); d[3] = f2bf(v.w);
  }
  __syncthreads();
  int n = tid >> 2, cs = (tid & 3) * 16;
  unsigned short tmp[16];
#pragma unroll
  for (int i = 0; i < 16; ++i) tmp[i] = sT[(cs + i) * 68 + n];
  unsigned short* dst = xbfT + (((size_t)b * 16384 + n0 + n) << 8) + c0 + cs;
  *reinterpret_cast<uint4*>(dst) = *reinterpret_cast<uint4*>(tmp);
  *reinterpret_cast<uint4*>(dst + 8) = *reinterpret_cast<uint4*>(tmp + 8);
}

// ---------------- prep (merged): wpb, BN scale/shift, pwPack, wqPack ----------------
__global__ __launch_bounds__(256) void prep_all(const float* __restrict__ wproj,
                                                const float* __restrict__ bng,
                                                const float* __restrict__ bnb,
                                                const float* __restrict__ bnm,
                                                const float* __restrict__ bnv,
                                                const float* __restrict__ pww,
                                                const float* __restrict__ wq,
                                                unsigned short* __restrict__ wpb,
                                                float* __restrict__ bnsc,
                                                float* __restrict__ bnsh,
                                                unsigned short* __restrict__ pwPack,
                                                unsigned short* __restrict__ wqPack) {
  int i = blockIdx.x * 256 + threadIdx.x;
  if (i < 32768) {
    int j = i & 7, lane = (i >> 3) & 63, kc = (i >> 9) & 7, ctcg = i >> 12;
    int row = (ctcg >> 2) * 128 + (ctcg & 3) * 32 + (lane & 31);
    int col = kc * 16 + (lane >> 5) * 8 + j;
    wpb[i] = f2bf(wproj[row * 128 + col]);
  } else if (i < 33024) {
    int c = i - 32768;
    float inv = bng[c] / sqrtf(bnv[c] + EPSV);
    bnsc[c] = inv;
    bnsh[c] = bnb[c] - bnm[c] * inv;
  } else if (i < 98560) {
    int f = i - 33024;
    int j = f & 7, lane = (f >> 3) & 63, ks = (f >> 9) & 15, mt = f >> 13;
    int o = mt * 32 + (lane & 31);
    int cc = ks * 16 + (lane >> 5) * 8 + j;
    pwPack[f] = f2bf(pww[o * 256 + cc]);
  } else if (i < 114944) {
    int g = i - 98560;
    int j = g & 7, lane = (g >> 3) & 63, ks = (g >> 9) & 15, mt = g >> 13;
    int o = mt * 32 + (lane & 31);
    int cc = ks * 16 + (lane >> 5) * 8 + j;
    wqPack[g] = f2bf(wq[o * 256 + cc] * 0.18033688011112042f);  // 0.125*log2(e)
  }
}

// ---------------- merged K+V GEMM: y==0 -> Kt (transposed out), y>0 -> Vbf -------------
__global__ __launch_bounds__(256, 4) void gemm_kv(const float* __restrict__ wk,
                                                  const float* __restrict__ wv,
                                                  const float* __restrict__ X,
                                                  unsigned short* __restrict__ Kt,
                                                  unsigned short* __restrict__ Vbf) {
  __shared__ float sW[64 * 68];
  __shared__ float sX[64 * 68];
  const int tid = threadIdx.x;
  const int n0 = blockIdx.x * 64;
  const int part = blockIdx.y;            // 0: K, 1/2: V halves
  const int m0 = (part == 0) ? 0 : (part - 1) * 64;
  const float* W = (part == 0) ? wk : wv;
  const size_t xoff = (size_t)blockIdx.z * 256 * 1024;
  const int tm4 = (tid >> 4) * 4, tn4 = (tid & 15) * 4;
  float acc[4][4] = {};
  for (int k0 = 0; k0 < 256; k0 += 64) {
    __syncthreads();
#pragma unroll
    for (int i = 0; i < 16; ++i) {
      int flat = tid + i * 256;
      int kk = flat & 63, mm = flat >> 6;
      sW[kk * 68 + mm] = W[(m0 + mm) * 256 + k0 + kk];
      sX[kk * 68 + mm] = X[xoff + (size_t)(k0 + kk) * 1024 + n0 + mm];
    }
    __syncthreads();
#pragma unroll 8
    for (int k = 0; k < 64; ++k) {
      float4 a4 = *reinterpret_cast<const float4*>(&sW[k * 68 + tm4]);
      float4 b4 = *reinterpret_cast<const float4*>(&sX[k * 68 + tn4]);
      float av[4] = {a4.x, a4.y, a4.z, a4.w};
      float bv[4] = {b4.x, b4.y, b4.z, b4.w};
#pragma unroll
      for (int i = 0; i < 4; ++i)
#pragma unroll
        for (int j = 0; j < 4; ++j) acc[i][j] += av[i] * bv[j];
    }
  }
  if (part == 0) {  // Kt[b][m(1024)][a(64)]
    const size_t coff = (size_t)blockIdx.z * 65536;
#pragma unroll
    for (int j = 0; j < 4; ++j) {
      ushort4 o;
      o.x = f2bf(acc[0][j]); o.y = f2bf(acc[1][j]);
      o.z = f2bf(acc[2][j]); o.w = f2bf(acc[3][j]);
      *reinterpret_cast<ushort4*>(&Kt[coff + (size_t)(n0 + tn4 + j) * 64 + tm4]) = o;
    }
  } else {  // Vbf[b][vc(128)][m(1024)]
    const size_t coff = (size_t)blockIdx.z * 131072;
#pragma unroll
    for (int i = 0; i < 4; ++i) {
      ushort4 o;
      o.x = f2bf(acc[i][0]); o.y = f2bf(acc[i][1]);
      o.z = f2bf(acc[i][2]); o.w = f2bf(acc[i][3]);
      *reinterpret_cast<ushort4*>(&Vbf[coff + (size_t)(m0 + tm4 + i) * 1024 + n0 + tn4]) = o;
    }
  }
}

// ---------------- Q GEMM via MFMA: Qt[b][n][64a] = (wqPack @ xbfT^T)^T ----------------
__global__ __launch_bounds__(256, 4) void qgemm_mfma(const unsigned short* __restrict__ xbfT,
                                                     const unsigned short* __restrict__ wqPack,
                                                     unsigned short* __restrict__ Qt) {
  __shared__ __align__(16) unsigned short sX[2][128 * 64];  // 32 KB
  const int tid = threadIdx.x;
  const int w = tid >> 6, l = tid & 63;
  const int lq = l & 31, hi = l >> 5;
  const int b = blockIdx.y;
  const int n0 = blockIdx.x * 128;
  const int lr8 = l >> 3;
  const int gslot = (l & 7) ^ (lr8 & 7);
  const unsigned short* xb = xbfT + (((size_t)b * 16384 + n0) << 8);

#define QSTAGE(buf, ck)                                                       \
  {                                                                           \
    _Pragma("unroll") for (int i = 0; i < 4; ++i) {                           \
      int row = w * 32 + i * 8;                                               \
      gload16(xb + ((size_t)(row + lr8) << 8) + (ck) * 64 + gslot * 8,        \
              &sX[buf][row * 64]);                                            \
    }                                                                         \
  }

  f32x16 acc0, acc1;
#pragma unroll
  for (int i = 0; i < 16; ++i) { acc0[i] = 0.f; acc1[i] = 0.f; }

  QSTAGE(0, 0);
  __syncthreads();
  int cur = 0;
  for (int ck = 0; ck < 4; ++ck) {
    if (ck < 3) QSTAGE(cur ^ 1, ck + 1);
    const unsigned short* xl = sX[cur];
#pragma unroll
    for (int k2 = 0; k2 < 4; ++k2) {
      bf16x8 bfr = ld_frag(xl + (w * 32 + lq) * 64 + (((2 * k2 + hi) ^ (lq & 7)) << 3));
      int ks = ck * 4 + k2;
      bf16x8 a0 = ld_frag(wqPack + (size_t)((ks)*64 + l) * 8);
      bf16x8 a1 = ld_frag(wqPack + (size_t)((16 + ks) * 64 + l) * 8);
      acc0 = __builtin_amdgcn_mfma_f32_32x32x16_bf16(a0, bfr, acc0, 0, 0, 0);
      acc1 = __builtin_amdgcn_mfma_f32_32x32x16_bf16(a1, bfr, acc1, 0, 0, 0);
    }
    __syncthreads();
    cur ^= 1;
  }
#undef QSTAGE

  unsigned short* so2 = (unsigned short*)sX + w * 2304;  // 32*72
#pragma unroll
  for (int r = 0; r < 16; ++r) {
    int a = (r & 3) + 8 * (r >> 2) + 4 * hi;
    so2[lq * 72 + a] = f2bf(acc0[r]);
    so2[lq * 72 + 32 + a] = f2bf(acc1[r]);
  }
#pragma unroll
  for (int pass = 0; pass < 4; ++pass) {
    int flat = pass * 64 + l;
    int row = flat >> 3, col8 = (flat & 7) * 8;
    bf16x8 v = ld_frag(so2 + row * 72 + col8);
    *reinterpret_cast<bf16x8*>(Qt + ((size_t)b * 16384 + n0 + w * 32 + row) * 64 + col8) = v;
  }
}

// ---------------- MFMA flash attention + proj + BN + SiLU -> yact bf16 ----------------
// Round-8 exact (do not touch): batch-major grid, syncthreads double-buffer loop,
// static-max base-2 softmax (p = 2^(s-16)), ones-MFMA row-sum, divide epilogue.
__global__ __launch_bounds__(256, 3) void attn_mfma(
    const unsigned short* __restrict__ Qt, const unsigned short* __restrict__ Kt,
    const unsigned short* __restrict__ Vb, const unsigned short* __restrict__ wpb,
    const float* __restrict__ bnsc, const float* __restrict__ bnsh,
    unsigned short* __restrict__ yact) {
  __shared__ __align__(16) unsigned char smem[49152];
  unsigned short* const sK = (unsigned short*)smem;            // [2][64][64]
  unsigned short* const sV = (unsigned short*)(smem + 16384);  // [2][128][64]
  const int tid = threadIdx.x;
  const int w = tid >> 6, l = tid & 63;
  const int lq = l & 31, hi = l >> 5;
  const int bid = blockIdx.x;
  const int b = bid >> 7;
  const int q0 = (bid & 127) * 128 + w * 32;

  const unsigned short* Qp = Qt + ((size_t)b * 16384 + q0 + lq) * 64 + hi * 8;
  bf16x8 qf[4];
#pragma unroll
  for (int kc = 0; kc < 4; ++kc) qf[kc] = ld_frag(Qp + kc * 16);

  const uint4v ow = {0x3F803F80u, 0x3F803F80u, 0x3F803F80u, 0x3F803F80u};
  const bf16x8 onesf = __builtin_bit_cast(bf16x8, ow);

  f32x16 acc[4], accS;
#pragma unroll
  for (int t = 0; t < 4; ++t)
#pragma unroll
    for (int i = 0; i < 16; ++i) acc[t][i] = 0.f;
#pragma unroll
  for (int i = 0; i < 16; ++i) accS[i] = 0.f;

  const unsigned short* Kb = Kt + (size_t)b * 65536;
  const unsigned short* Vbb = Vb + (size_t)b * 131072;
  const int lr8 = l >> 3;
  const int gslot = (l & 7) ^ (lr8 & 7);

#define STAGE(buf, ch)                                                           \
  {                                                                              \
    const int m0s = (ch) * 64;                                                   \
    _Pragma("unroll") for (int i = 0; i < 2; ++i) {                              \
      int row8 = w * 16 + i * 8;                                                 \
      gload16(Kb + (size_t)(m0s + row8 + lr8) * 64 + gslot * 8,                  \
              sK + (buf) * 4096 + row8 * 64);                                    \
    }                                                                            \
    _Pragma("unroll") for (int j = 0; j < 4; ++j) {                              \
      int vc8 = w * 32 + j * 8;                                                  \
      gload16(Vbb + (size_t)(vc8 + lr8) * 1024 + m0s + gslot * 8,                \
              sV + (buf) * 8192 + vc8 * 64);                                     \
    }                                                                            \
  }

  STAGE(0, 0);
  __syncthreads();
  int cur = 0;
  for (int ch = 0; ch < 16; ++ch) {
    if (ch < 15) STAGE(cur ^ 1, ch + 1);
    const unsigned short* kb = sK + cur * 4096;
    const unsigned short* vb = sV + cur * 8192;
#pragma unroll
    for (int msi = 0; msi < 2; ++msi) {
      const int ms = msi * 32;
      bf16x8 kf[4];
#pragma unroll
      for (int kc = 0; kc < 4; ++kc)
        kf[kc] = ld_frag(kb + (ms + lq) * 64 + (((2 * kc + hi) ^ (lq & 7)) << 3));
      f32x16 sa;
#pragma unroll
      for (int i = 0; i < 16; ++i) sa[i] = 0.f;
      __builtin_amdgcn_s_setprio(1);
#pragma unroll
      for (int kc = 0; kc < 4; ++kc)
        sa = __builtin_amdgcn_mfma_f32_32x32x16_bf16(kf[kc], qf[kc], sa, 0, 0, 0);
      __builtin_amdgcn_s_setprio(0);

      // p = 2^(s - 16): static shift, exact softmax after final normalization
      float p[16];
#pragma unroll
      for (int r = 0; r < 16; ++r) p[r] = fexp2(sa[r] - 16.0f);

      unsigned int wpk[8];
#pragma unroll
      for (int i = 0; i < 8; ++i) wpk[i] = cvtpk(p[2 * i], p[2 * i + 1]);
      auto s01 = __builtin_amdgcn_permlane32_swap(wpk[0], wpk[2], false, false);
      auto s23 = __builtin_amdgcn_permlane32_swap(wpk[1], wpk[3], false, false);
      auto s45 = __builtin_amdgcn_permlane32_swap(wpk[4], wpk[6], false, false);
      auto s67 = __builtin_amdgcn_permlane32_swap(wpk[5], wpk[7], false, false);
      uint4v f0 = {(unsigned int)s01[0], (unsigned int)s23[0], (unsigned int)s01[1],
                   (unsigned int)s23[1]};
      uint4v f1 = {(unsigned int)s45[0], (unsigned int)s67[0], (unsigned int)s45[1],
                   (unsigned int)s67[1]};
      bf16x8 pf0 = __builtin_bit_cast(bf16x8, f0);
      bf16x8 pf1 = __builtin_bit_cast(bf16x8, f1);

      __builtin_amdgcn_s_setprio(1);
#pragma unroll
      for (int t = 0; t < 4; ++t) {
        bf16x8 vf0 =
            ld_frag(vb + (t * 32 + lq) * 64 + ((((ms >> 3) + hi) ^ (lq & 7)) << 3));
        bf16x8 vf1 =
            ld_frag(vb + (t * 32 + lq) * 64 + ((((ms >> 3) + 2 + hi) ^ (lq & 7)) << 3));
        acc[t] = __builtin_amdgcn_mfma_f32_32x32x16_bf16(pf0, vf0, acc[t], 0, 0, 0);
        acc[t] = __builtin_amdgcn_mfma_f32_32x32x16_bf16(pf1, vf1, acc[t], 0, 0, 0);
      }
      accS = __builtin_amdgcn_mfma_f32_32x32x16_bf16(pf0, onesf, accS, 0, 0, 0);
      accS = __builtin_amdgcn_mfma_f32_32x32x16_bf16(pf1, onesf, accS, 0, 0, 0);
      __builtin_amdgcn_s_setprio(0);
    }
    __syncthreads();
    cur ^= 1;
  }
#undef STAGE

  unsigned short* so = (unsigned short*)smem + w * 4096;
#pragma unroll
  for (int t = 0; t < 4; ++t)
#pragma unroll
    for (int r = 0; r < 16; ++r) {
      int q = (r & 3) + 8 * (r >> 2) + 4 * hi;
      int col = t * 32 + lq;
      so[q * 128 + (col ^ ((q & 15) << 3))] = f2bf(acc[t][r] / accS[r]);
    }
  __syncthreads();

  bf16x8 of[8];
#pragma unroll
  for (int kc = 0; kc < 8; ++kc) {
    int colr = kc * 16 + hi * 8;
    of[kc] = ld_frag(&so[lq * 128 + (colr ^ ((lq & 15) << 3))]);
  }
#pragma unroll
  for (int cg = 0; cg < 2; ++cg) {
    f32x16 z[4];
#pragma unroll
    for (int t = 0; t < 4; ++t)
#pragma unroll
      for (int i = 0; i < 16; ++i) z[t][i] = 0.f;
#pragma unroll
    for (int ct = 0; ct < 4; ++ct) {
      const unsigned short* wp = wpb + (size_t)(cg * 4 + ct) * 4096 + (size_t)l * 8;
#pragma unroll
      for (int kc = 0; kc < 8; ++kc) {
        bf16x8 wf = ld_frag(wp + kc * 512);
        z[ct] = __builtin_amdgcn_mfma_f32_32x32x16_bf16(wf, of[kc], z[ct], 0, 0, 0);
      }
    }
#pragma unroll
    for (int ct = 0; ct < 4; ++ct)
#pragma unroll
      for (int r = 0; r < 16; ++r) {
        int c = cg * 128 + ct * 32 + (r & 3) + 8 * (r >> 2) + 4 * hi;
        float val = z[ct][r] * bnsc[c] + bnsh[c];
        yact[((size_t)(b * 256 + c)) * 16384 + q0 + lq] = f2bf(silu_f(val));
      }
  }
}

// ------- FUSED dw3x3 + pointwise mix + BN + SiLU + residual (replaces dwconv+pwmix) -----
// Per block (h,b): compute D[256c][128px] in 16-channel chunks from yact rows h-1..h+1
// directly into pwmix's swizzled sDt layout, then MFMA mix + epilogue. Saves the 134 MB
// D round-trip.
__global__ __launch_bounds__(256, 2) void dwpw_fused(
    const unsigned short* __restrict__ yact, const float* __restrict__ dww,
    const unsigned short* __restrict__ pwPack, const float* __restrict__ x,
    const float* __restrict__ mg, const float* __restrict__ mb2,
    const float* __restrict__ mmu, const float* __restrict__ mvv,
    float* __restrict__ out) {
  __shared__ unsigned int sDt[16384];          // 64 KB, layout identical to old pwmix
  __shared__ unsigned short sH[16 * 3 * 132];  // 12.4 KB halo: [cc][r][1+px], pads zero
  __shared__ float smsc[256], smsh[256];
  const int tid = threadIdx.x;
  const int w = tid >> 6, l = tid & 63;
  const int lq = l & 31, hi = l >> 5;
  const int h = blockIdx.x, b = blockIdx.y;
  if (tid < 256) {
    float inv = mg[tid] * rsqrtf(mvv[tid] + EPSV);
    smsc[tid] = inv;
    smsh[tid] = mb2[tid] - mmu[tid] * inv;
  }
  for (int s = tid; s < 16 * 3 * 132; s += 256) sH[s] = 0;

  const int cpl = tid >> 5;        // 0..7  (local channel-pair)
  const int px0 = (tid & 31) * 4;  // 4 output px per thread

  for (int chunk = 0; chunk < 16; ++chunk) {
    __syncthreads();  // prev chunk's sH reads done (and zero-init on first iter)
    const int c0 = chunk * 16;
    // stage yact rows h-1..h+1 for 16 channels (768 units of 8 px)
#pragma unroll
    for (int i = 0; i < 3; ++i) {
      int u = tid + i * 256;
      int cc = u / 48, rem = u % 48;
      int r = rem >> 4, pxg = rem & 15;
      int hr = h - 1 + r;
      uint4v vz = {0u, 0u, 0u, 0u};
      bf16x8 v = __builtin_bit_cast(bf16x8, vz);
      if (hr >= 0 && hr < 128)
        v = ld_frag(yact + (size_t)(b * 256 + c0 + cc) * 16384 + hr * 128 + pxg * 8);
      *reinterpret_cast<bf16x8*>(&sH[(cc * 3 + r) * 132 + 1 + pxg * 8]) = v;
    }
    __syncthreads();
    // dwconv for channels {2cpl, 2cpl+1} x px0..px0+3, pack into sDt
    float d0[4] = {}, d1[4] = {};
#pragma unroll
    for (int e = 0; e < 2; ++e) {
      int cc = cpl * 2 + e;
      const float* w9 = dww + (c0 + cc) * 9;
      float wr[9];
#pragma unroll
      for (int k = 0; k < 9; ++k) wr[k] = w9[k];
      float* dd = e ? d1 : d0;
#pragma unroll
      for (int r = 0; r < 3; ++r) {
        const unsigned int* rw =
            reinterpret_cast<const unsigned int*>(&sH[(cc * 3 + r) * 132 + px0]);
        unsigned int w0 = rw[0], w1 = rw[1], w2 = rw[2];
        float fr[6] = {bfu_lo(w0), bfu_hi(w0), bfu_lo(w1),
                       bfu_hi(w1), bfu_lo(w2), bfu_hi(w2)};
#pragma unroll
        for (int p = 0; p < 4; ++p)
          dd[p] += fr[p] * wr[r * 3] + fr[p + 1] * wr[r * 3 + 1] + fr[p + 2] * wr[r * 3 + 2];
      }
    }
#pragma unroll
    for (int p = 0; p < 4; ++p) {
      int px = px0 + p;
      int widx = (px * 128 + chunk * 8 + cpl) ^ ((px & 7) << 2);
      sDt[widx] = cvtpk(d0[p], d1[p]);
    }
  }
  __syncthreads();

  // ---- pointwise mix MFMA (unchanged from pwmix) ----
  f32x16 z[2][4];
#pragma unroll
  for (int mti = 0; mti < 2; ++mti)
#pragma unroll
    for (int nt = 0; nt < 4; ++nt)
#pragma unroll
      for (int i = 0; i < 16; ++i) z[mti][nt][i] = 0.f;

#pragma unroll
  for (int ks = 0; ks < 16; ++ks) {
    bf16x8 a0 = ld_frag(pwPack + (size_t)(((w * 2 + 0) * 16 + ks) * 64 + l) * 8);
    bf16x8 a1 = ld_frag(pwPack + (size_t)(((w * 2 + 1) * 16 + ks) * 64 + l) * 8);
    bf16x8 bfr[4];
#pragma unroll
    for (int nt = 0; nt < 4; ++nt) {
      int word = ((nt * 32 + lq) * 128 + 8 * ks + 4 * hi) ^ ((lq & 7) << 2);
      bfr[nt] = *reinterpret_cast<const bf16x8*>(
          reinterpret_cast<const unsigned short*>(sDt) + (size_t)word * 2);
    }
#pragma unroll
    for (int nt = 0; nt < 4; ++nt) {
      z[0][nt] = __builtin_amdgcn_mfma_f32_32x32x16_bf16(a0, bfr[nt], z[0][nt], 0, 0, 0);
      z[1][nt] = __builtin_amdgcn_mfma_f32_32x32x16_bf16(a1, bfr[nt], z[1][nt], 0, 0, 0);
    }
  }

#pragma unroll
  for (int mti = 0; mti < 2; ++mti) {
    int ob = (w * 2 + mti) * 32 + 4 * hi;
#pragma unroll
    for (int r = 0; r < 16; ++r) {
      int o = ob + (r & 3) + 8 * (r >> 2);
      float sc = smsc[o], sh = smsh[o];
#pragma unroll
      for (int nt = 0; nt < 4; ++nt) {
        int px = nt * 32 + lq;
        size_t gi = (((size_t)(b * 256 + o)) << 14) + (size_t)h * 128 + px;
        float val = z[mti][nt][r] * sc + sh;
        out[gi] = x[gi] + silu_f(val);
      }
    }
  }
}

extern "C" void kernel_launch(void* const* d_in, const int* in_sizes, int n_in,
                              void* d_out, int out_size, void* d_ws, size_t ws_size,
                              hipStream_t stream) {
  const float* x     = (const float*)d_in[0];
  const float* wq    = (const float*)d_in[1];
  const float* wk    = (const float*)d_in[2];
  const float* wvp   = (const float*)d_in[3];
  const float* wproj = (const float*)d_in[4];
  const float* bng   = (const float*)d_in[5];
  const float* bnb   = (const float*)d_in[6];
  const float* bnm   = (const float*)d_in[7];
  const float* bnv   = (const float*)d_in[8];
  const float* dww   = (const float*)d_in[9];
  const float* pww   = (const float*)d_in[10];
  const float* mg    = (const float*)d_in[11];
  const float* mb2   = (const float*)d_in[12];
  const float* mmu   = (const float*)d_in[13];
  const float* mvv   = (const float*)d_in[14];
  float* out = (float*)d_out;

  char* base = (char*)d_ws;
  float* xkv = (float*)base;                                   //  8,388,608 B
  unsigned short* Qt  = (unsigned short*)(base + 8388608);     // 16,777,216 B
  unsigned short* Kt  = (unsigned short*)(base + 25165824);    //  1,048,576 B
  unsigned short* Vbf = (unsigned short*)(base + 26214400);    //  2,097,152 B
  unsigned short* wqPack = (unsigned short*)(base + 28311552); //     32,768 B
  float* bnsc = (float*)(base + 67108864);
  float* bnsh = (float*)(base + 67109888);
  unsigned short* wpb    = (unsigned short*)(base + 67110912);
  unsigned short* pwPack = (unsigned short*)(base + 67176448);
  unsigned short* yact   = (unsigned short*)(base + 67307520); // 67,108,864 B
  unsigned short* xbfT   = yact;  // aliases yact: xbfT dead before attn writes yact

  cvtT_kernel<<<dim3(256, 4, 8), 256, 0, stream>>>(x, xbfT);
  pool_kernel<<<8192, 256, 0, stream>>>(x, xkv);
  prep_all<<<449, 256, 0, stream>>>(wproj, bng, bnb, bnm, bnv, pww, wq, wpb, bnsc, bnsh,
                                    pwPack, wqPack);
  gemm_kv<<<dim3(16, 3, 8), 256, 0, stream>>>(wk, wvp, xkv, Kt, Vbf);
  qgemm_mfma<<<dim3(128, 8), 256, 0, stream>>>(xbfT, wqPack, Qt);
  attn_mfma<<<dim3(1024), 256, 0, stream>>>(Qt, Kt, Vbf, wpb, bnsc, bnsh, yact);
  dwpw_fused<<<dim3(128, 8), 256, 0, stream>>>(yact, dww, pwPack, x, mg, mb2, mmu, mvv,
                                               out);
}

// Round 14
// 279.725 us; speedup vs baseline: 1.2573x; 1.2573x over previous
//
#include <hip/hip_runtime.h>
#include <hip/hip_bf16.h>
#include <math.h>

#define EPSV 1e-5f

typedef short bf16x8 __attribute__((ext_vector_type(8)));
typedef float f32x16 __attribute__((ext_vector_type(16)));
typedef unsigned int uint4v __attribute__((ext_vector_type(4)));

__device__ __forceinline__ float silu_f(float v) { return v / (1.0f + __expf(-v)); }

__device__ __forceinline__ unsigned short f2bf(float f) {
  __hip_bfloat16 h = __float2bfloat16(f);
  return __builtin_bit_cast(unsigned short, h);
}

__device__ __forceinline__ float bf2f(unsigned short u) {
  return __builtin_bit_cast(float, (unsigned int)u << 16);
}

// hardware 2^x (VOP1 v_exp_f32)
__device__ __forceinline__ float fexp2(float x) {
  float r;
  asm("v_exp_f32 %0, %1" : "=v"(r) : "v"(x));
  return r;
}

// packed f32x2 -> bf16x2 (low = lo, high = hi)
__device__ __forceinline__ unsigned int cvtpk(float lo, float hi) {
  unsigned int r;
  asm("v_cvt_pk_bf16_f32 %0, %1, %2" : "=v"(r) : "v"(lo), "v"(hi));
  return r;
}

__device__ __forceinline__ bf16x8 ld_frag(const unsigned short* p) {
  return *reinterpret_cast<const bf16x8*>(p);
}

__device__ __forceinline__ void gload16(const unsigned short* g, unsigned short* l) {
  __builtin_amdgcn_global_load_lds((const __attribute__((address_space(1))) void*)g,
                                   (__attribute__((address_space(3))) void*)l, 16, 0, 0);
}

// ---------------- cvt+transpose: x fp32 [b][c][n] -> xbfT bf16 [b][n][c] ----------------
__global__ __launch_bounds__(256) void cvtT_kernel(const float* __restrict__ x,
                                                   unsigned short* __restrict__ xbfT) {
  __shared__ unsigned short sT[64 * 68];
  const int tid = threadIdx.x;
  const int b = blockIdx.z, c0 = blockIdx.y * 64, n0 = blockIdx.x * 64;
  const float* xs = x + ((size_t)(b * 256 + c0) << 14) + n0;
#pragma unroll
  for (int pass = 0; pass < 4; ++pass) {
    int cc = (tid >> 4) + pass * 16;
    int col = (tid & 15) * 4;
    float4 v = *reinterpret_cast<const float4*>(xs + ((size_t)cc << 14) + col);
    unsigned short* d = &sT[cc * 68 + col];
    d[0] = f2bf(v.x); d[1] = f2bf(v.y); d[2] = f2bf(v.z); d[3] = f2bf(v.w);
  }
  __syncthreads();
  int n = tid >> 2, cs = (tid & 3) * 16;
  unsigned short tmp[16];
#pragma unroll
  for (int i = 0; i < 16; ++i) tmp[i] = sT[(cs + i) * 68 + n];
  unsigned short* dst = xbfT + (((size_t)b * 16384 + n0 + n) << 8) + c0 + cs;
  *reinterpret_cast<uint4*>(dst) = *reinterpret_cast<uint4*>(tmp);
  *reinterpret_cast<uint4*>(dst + 8) = *reinterpret_cast<uint4*>(tmp + 8);
}

// ---------------- 4x4 pool from xbfT (bf16 [b][n][c]) -> xkv fp32 [b][c][32][32] -------
// Reads the L3-warm 67MB xbfT instead of re-reading the 134MB fp32 x.
__global__ __launch_bounds__(256) void pool2_kernel(const unsigned short* __restrict__ xbfT,
                                                    float* __restrict__ xkv) {
  const int tid = threadIdx.x;
  const int w = tid >> 6, l = tid & 63;
  const int half = blockIdx.x & 1, hh = blockIdx.x >> 1;  // grid (64, 8)
  const int b = blockIdx.y;
  const int c0 = l * 4;
  float acc[4][4] = {};
#pragma unroll
  for (int wwi = 0; wwi < 4; ++wwi) {
    int ww = half * 16 + w * 4 + wwi;
#pragma unroll
    for (int i = 0; i < 4; ++i)
#pragma unroll
      for (int j = 0; j < 4; ++j) {
        int n = (4 * hh + i) * 128 + 4 * ww + j;
        ushort4 v = *reinterpret_cast<const ushort4*>(xbfT + (((size_t)b * 16384 + n) << 8) +
                                                      c0);
        acc[wwi][0] += bf2f(v.x);
        acc[wwi][1] += bf2f(v.y);
        acc[wwi][2] += bf2f(v.z);
        acc[wwi][3] += bf2f(v.w);
      }
  }
#pragma unroll
  for (int cc = 0; cc < 4; ++cc) {
    float4 o = make_float4(acc[0][cc] * 0.0625f, acc[1][cc] * 0.0625f, acc[2][cc] * 0.0625f,
                           acc[3][cc] * 0.0625f);
    float* dst = xkv + (((size_t)(b * 256 + c0 + cc)) << 10) + hh * 32 + half * 16 + w * 4;
    *reinterpret_cast<float4*>(dst) = o;
  }
}

// ---------------- prep (merged): wpb, BN scale/shift, pwPack, wqPack ----------------
__global__ __launch_bounds__(256) void prep_all(const float* __restrict__ wproj,
                                                const float* __restrict__ bng,
                                                const float* __restrict__ bnb,
                                                const float* __restrict__ bnm,
                                                const float* __restrict__ bnv,
                                                const float* __restrict__ pww,
                                                const float* __restrict__ wq,
                                                unsigned short* __restrict__ wpb,
                                                float* __restrict__ bnsc,
                                                float* __restrict__ bnsh,
                                                unsigned short* __restrict__ pwPack,
                                                unsigned short* __restrict__ wqPack) {
  int i = blockIdx.x * 256 + threadIdx.x;
  if (i < 32768) {
    int j = i & 7, lane = (i >> 3) & 63, kc = (i >> 9) & 7, ctcg = i >> 12;
    int row = (ctcg >> 2) * 128 + (ctcg & 3) * 32 + (lane & 31);
    int col = kc * 16 + (lane >> 5) * 8 + j;
    wpb[i] = f2bf(wproj[row * 128 + col]);
  } else if (i < 33024) {
    int c = i - 32768;
    float inv = bng[c] / sqrtf(bnv[c] + EPSV);
    bnsc[c] = inv;
    bnsh[c] = bnb[c] - bnm[c] * inv;
  } else if (i < 98560) {
    int f = i - 33024;
    int j = f & 7, lane = (f >> 3) & 63, ks = (f >> 9) & 15, mt = f >> 13;
    int o = mt * 32 + (lane & 31);
    int cc = ks * 16 + (lane >> 5) * 8 + j;
    pwPack[f] = f2bf(pww[o * 256 + cc]);
  } else if (i < 114944) {
    int g = i - 98560;
    int j = g & 7, lane = (g >> 3) & 63, ks = (g >> 9) & 15, mt = g >> 13;
    int o = mt * 32 + (lane & 31);
    int cc = ks * 16 + (lane >> 5) * 8 + j;
    wqPack[g] = f2bf(wq[o * 256 + cc] * 0.18033688011112042f);  // 0.125*log2(e)
  }
}

// ---------------- merged K+V GEMM: y==0 -> Kt (transposed out), y>0 -> Vbf -------------
__global__ __launch_bounds__(256, 4) void gemm_kv(const float* __restrict__ wk,
                                                  const float* __restrict__ wv,
                                                  const float* __restrict__ X,
                                                  unsigned short* __restrict__ Kt,
                                                  unsigned short* __restrict__ Vbf) {
  __shared__ float sW[64 * 68];
  __shared__ float sX[64 * 68];
  const int tid = threadIdx.x;
  const int n0 = blockIdx.x * 64;
  const int part = blockIdx.y;            // 0: K, 1/2: V halves
  const int m0 = (part == 0) ? 0 : (part - 1) * 64;
  const float* W = (part == 0) ? wk : wv;
  const size_t xoff = (size_t)blockIdx.z * 256 * 1024;
  const int tm4 = (tid >> 4) * 4, tn4 = (tid & 15) * 4;
  float acc[4][4] = {};
  for (int k0 = 0; k0 < 256; k0 += 64) {
    __syncthreads();
#pragma unroll
    for (int i = 0; i < 16; ++i) {
      int flat = tid + i * 256;
      int kk = flat & 63, mm = flat >> 6;
      sW[kk * 68 + mm] = W[(m0 + mm) * 256 + k0 + kk];
      sX[kk * 68 + mm] = X[xoff + (size_t)(k0 + kk) * 1024 + n0 + mm];
    }
    __syncthreads();
#pragma unroll 8
    for (int k = 0; k < 64; ++k) {
      float4 a4 = *reinterpret_cast<const float4*>(&sW[k * 68 + tm4]);
      float4 b4 = *reinterpret_cast<const float4*>(&sX[k * 68 + tn4]);
      float av[4] = {a4.x, a4.y, a4.z, a4.w};
      float bv[4] = {b4.x, b4.y, b4.z, b4.w};
#pragma unroll
      for (int i = 0; i < 4; ++i)
#pragma unroll
        for (int j = 0; j < 4; ++j) acc[i][j] += av[i] * bv[j];
    }
  }
  if (part == 0) {  // Kt[b][m(1024)][a(64)]
    const size_t coff = (size_t)blockIdx.z * 65536;
#pragma unroll
    for (int j = 0; j < 4; ++j) {
      ushort4 o;
      o.x = f2bf(acc[0][j]); o.y = f2bf(acc[1][j]);
      o.z = f2bf(acc[2][j]); o.w = f2bf(acc[3][j]);
      *reinterpret_cast<ushort4*>(&Kt[coff + (size_t)(n0 + tn4 + j) * 64 + tm4]) = o;
    }
  } else {  // Vbf[b][vc(128)][m(1024)]
    const size_t coff = (size_t)blockIdx.z * 131072;
#pragma unroll
    for (int i = 0; i < 4; ++i) {
      ushort4 o;
      o.x = f2bf(acc[i][0]); o.y = f2bf(acc[i][1]);
      o.z = f2bf(acc[i][2]); o.w = f2bf(acc[i][3]);
      *reinterpret_cast<ushort4*>(&Vbf[coff + (size_t)(m0 + tm4 + i) * 1024 + n0 + tn4]) = o;
    }
  }
}

// ---------------- Q GEMM via MFMA: Qt[b][n][64a] = (wqPack @ xbfT^T)^T ----------------
__global__ __launch_bounds__(256, 4) void qgemm_mfma(const unsigned short* __restrict__ xbfT,
                                                     const unsigned short* __restrict__ wqPack,
                                                     unsigned short* __restrict__ Qt) {
  __shared__ __align__(16) unsigned short sX[2][128 * 64];  // 32 KB
  const int tid = threadIdx.x;
  const int w = tid >> 6, l = tid & 63;
  const int lq = l & 31, hi = l >> 5;
  const int b = blockIdx.y;
  const int n0 = blockIdx.x * 128;
  const int lr8 = l >> 3;
  const int gslot = (l & 7) ^ (lr8 & 7);
  const unsigned short* xb = xbfT + (((size_t)b * 16384 + n0) << 8);

#define QSTAGE(buf, ck)                                                       \
  {                                                                           \
    _Pragma("unroll") for (int i = 0; i < 4; ++i) {                           \
      int row = w * 32 + i * 8;                                               \
      gload16(xb + ((size_t)(row + lr8) << 8) + (ck) * 64 + gslot * 8,        \
              &sX[buf][row * 64]);                                            \
    }                                                                         \
  }

  f32x16 acc0, acc1;
#pragma unroll
  for (int i = 0; i < 16; ++i) { acc0[i] = 0.f; acc1[i] = 0.f; }

  QSTAGE(0, 0);
  __syncthreads();
  int cur = 0;
  for (int ck = 0; ck < 4; ++ck) {
    if (ck < 3) QSTAGE(cur ^ 1, ck + 1);
    const unsigned short* xl = sX[cur];
#pragma unroll
    for (int k2 = 0; k2 < 4; ++k2) {
      bf16x8 bfr = ld_frag(xl + (w * 32 + lq) * 64 + (((2 * k2 + hi) ^ (lq & 7)) << 3));
      int ks = ck * 4 + k2;
      bf16x8 a0 = ld_frag(wqPack + (size_t)((ks)*64 + l) * 8);
      bf16x8 a1 = ld_frag(wqPack + (size_t)((16 + ks) * 64 + l) * 8);
      acc0 = __builtin_amdgcn_mfma_f32_32x32x16_bf16(a0, bfr, acc0, 0, 0, 0);
      acc1 = __builtin_amdgcn_mfma_f32_32x32x16_bf16(a1, bfr, acc1, 0, 0, 0);
    }
    __syncthreads();
    cur ^= 1;
  }
#undef QSTAGE

  unsigned short* so2 = (unsigned short*)sX + w * 2304;  // 32*72
#pragma unroll
  for (int r = 0; r < 16; ++r) {
    int a = (r & 3) + 8 * (r >> 2) + 4 * hi;
    so2[lq * 72 + a] = f2bf(acc0[r]);
    so2[lq * 72 + 32 + a] = f2bf(acc1[r]);
  }
#pragma unroll
  for (int pass = 0; pass < 4; ++pass) {
    int flat = pass * 64 + l;
    int row = flat >> 3, col8 = (flat & 7) * 8;
    bf16x8 v = ld_frag(so2 + row * 72 + col8);
    *reinterpret_cast<bf16x8*>(Qt + ((size_t)b * 16384 + n0 + w * 32 + row) * 64 + col8) = v;
  }
}

// ---------------- MFMA flash attention + proj + BN + SiLU -> yact bf16 ----------------
// Round-8 exact (do not touch): batch-major grid, syncthreads double-buffer loop,
// static-max base-2 softmax (p = 2^(s-16)), ones-MFMA row-sum, divide epilogue.
__global__ __launch_bounds__(256, 3) void attn_mfma(
    const unsigned short* __restrict__ Qt, const unsigned short* __restrict__ Kt,
    const unsigned short* __restrict__ Vb, const unsigned short* __restrict__ wpb,
    const float* __restrict__ bnsc, const float* __restrict__ bnsh,
    unsigned short* __restrict__ yact) {
  __shared__ __align__(16) unsigned char smem[49152];
  unsigned short* const sK = (unsigned short*)smem;            // [2][64][64]
  unsigned short* const sV = (unsigned short*)(smem + 16384);  // [2][128][64]
  const int tid = threadIdx.x;
  const int w = tid >> 6, l = tid & 63;
  const int lq = l & 31, hi = l >> 5;
  const int bid = blockIdx.x;
  const int b = bid >> 7;
  const int q0 = (bid & 127) * 128 + w * 32;

  const unsigned short* Qp = Qt + ((size_t)b * 16384 + q0 + lq) * 64 + hi * 8;
  bf16x8 qf[4];
#pragma unroll
  for (int kc = 0; kc < 4; ++kc) qf[kc] = ld_frag(Qp + kc * 16);

  const uint4v ow = {0x3F803F80u, 0x3F803F80u, 0x3F803F80u, 0x3F803F80u};
  const bf16x8 onesf = __builtin_bit_cast(bf16x8, ow);

  f32x16 acc[4], accS;
#pragma unroll
  for (int t = 0; t < 4; ++t)
#pragma unroll
    for (int i = 0; i < 16; ++i) acc[t][i] = 0.f;
#pragma unroll
  for (int i = 0; i < 16; ++i) accS[i] = 0.f;

  const unsigned short* Kb = Kt + (size_t)b * 65536;
  const unsigned short* Vbb = Vb + (size_t)b * 131072;
  const int lr8 = l >> 3;
  const int gslot = (l & 7) ^ (lr8 & 7);

#define STAGE(buf, ch)                                                           \
  {                                                                              \
    const int m0s = (ch) * 64;                                                   \
    _Pragma("unroll") for (int i = 0; i < 2; ++i) {                              \
      int row8 = w * 16 + i * 8;                                                 \
      gload16(Kb + (size_t)(m0s + row8 + lr8) * 64 + gslot * 8,                  \
              sK + (buf) * 4096 + row8 * 64);                                    \
    }                                                                            \
    _Pragma("unroll") for (int j = 0; j < 4; ++j) {                              \
      int vc8 = w * 32 + j * 8;                                                  \
      gload16(Vbb + (size_t)(vc8 + lr8) * 1024 + m0s + gslot * 8,                \
              sV + (buf) * 8192 + vc8 * 64);                                     \
    }                                                                            \
  }

  STAGE(0, 0);
  __syncthreads();
  int cur = 0;
  for (int ch = 0; ch < 16; ++ch) {
    if (ch < 15) STAGE(cur ^ 1, ch + 1);
    const unsigned short* kb = sK + cur * 4096;
    const unsigned short* vb = sV + cur * 8192;
#pragma unroll
    for (int msi = 0; msi < 2; ++msi) {
      const int ms = msi * 32;
      bf16x8 kf[4];
#pragma unroll
      for (int kc = 0; kc < 4; ++kc)
        kf[kc] = ld_frag(kb + (ms + lq) * 64 + (((2 * kc + hi) ^ (lq & 7)) << 3));
      f32x16 sa;
#pragma unroll
      for (int i = 0; i < 16; ++i) sa[i] = 0.f;
      __builtin_amdgcn_s_setprio(1);
#pragma unroll
      for (int kc = 0; kc < 4; ++kc)
        sa = __builtin_amdgcn_mfma_f32_32x32x16_bf16(kf[kc], qf[kc], sa, 0, 0, 0);
      __builtin_amdgcn_s_setprio(0);

      // p = 2^(s - 16): static shift, exact softmax after final normalization
      float p[16];
#pragma unroll
      for (int r = 0; r < 16; ++r) p[r] = fexp2(sa[r] - 16.0f);

      unsigned int wpk[8];
#pragma unroll
      for (int i = 0; i < 8; ++i) wpk[i] = cvtpk(p[2 * i], p[2 * i + 1]);
      auto s01 = __builtin_amdgcn_permlane32_swap(wpk[0], wpk[2], false, false);
      auto s23 = __builtin_amdgcn_permlane32_swap(wpk[1], wpk[3], false, false);
      auto s45 = __builtin_amdgcn_permlane32_swap(wpk[4], wpk[6], false, false);
      auto s67 = __builtin_amdgcn_permlane32_swap(wpk[5], wpk[7], false, false);
      uint4v f0 = {(unsigned int)s01[0], (unsigned int)s23[0], (unsigned int)s01[1],
                   (unsigned int)s23[1]};
      uint4v f1 = {(unsigned int)s45[0], (unsigned int)s67[0], (unsigned int)s45[1],
                   (unsigned int)s67[1]};
      bf16x8 pf0 = __builtin_bit_cast(bf16x8, f0);
      bf16x8 pf1 = __builtin_bit_cast(bf16x8, f1);

      __builtin_amdgcn_s_setprio(1);
#pragma unroll
      for (int t = 0; t < 4; ++t) {
        bf16x8 vf0 =
            ld_frag(vb + (t * 32 + lq) * 64 + ((((ms >> 3) + hi) ^ (lq & 7)) << 3));
        bf16x8 vf1 =
            ld_frag(vb + (t * 32 + lq) * 64 + ((((ms >> 3) + 2 + hi) ^ (lq & 7)) << 3));
        acc[t] = __builtin_amdgcn_mfma_f32_32x32x16_bf16(pf0, vf0, acc[t], 0, 0, 0);
        acc[t] = __builtin_amdgcn_mfma_f32_32x32x16_bf16(pf1, vf1, acc[t], 0, 0, 0);
      }
      accS = __builtin_amdgcn_mfma_f32_32x32x16_bf16(pf0, onesf, accS, 0, 0, 0);
      accS = __builtin_amdgcn_mfma_f32_32x32x16_bf16(pf1, onesf, accS, 0, 0, 0);
      __builtin_amdgcn_s_setprio(0);
    }
    __syncthreads();
    cur ^= 1;
  }
#undef STAGE

  unsigned short* so = (unsigned short*)smem + w * 4096;
#pragma unroll
  for (int t = 0; t < 4; ++t)
#pragma unroll
    for (int r = 0; r < 16; ++r) {
      int q = (r & 3) + 8 * (r >> 2) + 4 * hi;
      int col = t * 32 + lq;
      so[q * 128 + (col ^ ((q & 15) << 3))] = f2bf(acc[t][r] / accS[r]);
    }
  __syncthreads();

  bf16x8 of[8];
#pragma unroll
  for (int kc = 0; kc < 8; ++kc) {
    int colr = kc * 16 + hi * 8;
    of[kc] = ld_frag(&so[lq * 128 + (colr ^ ((lq & 15) << 3))]);
  }
#pragma unroll
  for (int cg = 0; cg < 2; ++cg) {
    f32x16 z[4];
#pragma unroll
    for (int t = 0; t < 4; ++t)
#pragma unroll
      for (int i = 0; i < 16; ++i) z[t][i] = 0.f;
#pragma unroll
    for (int ct = 0; ct < 4; ++ct) {
      const unsigned short* wp = wpb + (size_t)(cg * 4 + ct) * 4096 + (size_t)l * 8;
#pragma unroll
      for (int kc = 0; kc < 8; ++kc) {
        bf16x8 wf = ld_frag(wp + kc * 512);
        z[ct] = __builtin_amdgcn_mfma_f32_32x32x16_bf16(wf, of[kc], z[ct], 0, 0, 0);
      }
    }
#pragma unroll
    for (int ct = 0; ct < 4; ++ct)
#pragma unroll
      for (int r = 0; r < 16; ++r) {
        int c = cg * 128 + ct * 32 + (r & 3) + 8 * (r >> 2) + 4 * hi;
        float val = z[ct][r] * bnsc[c] + bnsh[c];
        yact[((size_t)(b * 256 + c)) * 16384 + q0 + lq] = f2bf(silu_f(val));
      }
  }
}

// ---------------- depthwise 3x3: yact bf16 -> D bf16, one (b,c) plane per block --------
__global__ __launch_bounds__(256, 4) void dwconv_kernel(const unsigned short* __restrict__ yact,
                                                        const float* __restrict__ dww,
                                                        unsigned short* __restrict__ D) {
  __shared__ unsigned int sP[130 * 67];
  const int tid = threadIdx.x;
  const int bc = blockIdx.x;
  const int c = bc & 255;
  for (int s = tid; s < 130 * 67; s += 256) sP[s] = 0;
  __syncthreads();
  const unsigned int* ysrc = reinterpret_cast<const unsigned int*>(yact) + (size_t)bc * 8192;
#pragma unroll
  for (int i = 0; i < 8; ++i) {
    int wi4 = tid + 256 * i;
    uint4 v = *reinterpret_cast<const uint4*>(ysrc + (size_t)wi4 * 4);
    int row = wi4 >> 4;
    int cw = (wi4 & 15) * 4;
    unsigned int* dst = &sP[(row + 1) * 67 + 1 + cw];
    dst[0] = v.x; dst[1] = v.y; dst[2] = v.z; dst[3] = v.w;
  }
  __syncthreads();
  float w9[9];
#pragma unroll
  for (int k = 0; k < 9; ++k) w9[k] = dww[c * 9 + k];
#pragma unroll
  for (int it = 0; it < 4; ++it) {
    int u = tid + 256 * it;
    int rho = u >> 4;
    int wg = u & 15;
    float a0[8] = {}, a1[8] = {};
#pragma unroll
    for (int ir = 0; ir < 4; ++ir) {
      int srow = rho * 2 + ir;
      const unsigned int* rp = &sP[srow * 67 + 4 * wg];
      float f[12];
#pragma unroll
      for (int k = 0; k < 6; ++k) {
        unsigned int wv = rp[k];
        f[2 * k] = __builtin_bit_cast(float, wv << 16);
        f[2 * k + 1] = __builtin_bit_cast(float, wv & 0xffff0000u);
      }
      if (ir < 3) {
#pragma unroll
        for (int cc = 0; cc < 8; ++cc)
#pragma unroll
          for (int dc = 0; dc < 3; ++dc) a0[cc] += f[cc + 1 + dc] * w9[ir * 3 + dc];
      }
      if (ir > 0) {
#pragma unroll
        for (int cc = 0; cc < 8; ++cc)
#pragma unroll
          for (int dc = 0; dc < 3; ++dc) a1[cc] += f[cc + 1 + dc] * w9[(ir - 1) * 3 + dc];
      }
    }
    uint4v o0, o1;
#pragma unroll
    for (int k = 0; k < 4; ++k) {
      o0[k] = (unsigned int)f2bf(a0[2 * k]) | ((unsigned int)f2bf(a0[2 * k + 1]) << 16);
      o1[k] = (unsigned int)f2bf(a1[2 * k]) | ((unsigned int)f2bf(a1[2 * k + 1]) << 16);
    }
    size_t ob = (size_t)bc * 8192 + (size_t)(rho * 2) * 64 + wg * 4;
    unsigned int* Dw = reinterpret_cast<unsigned int*>(D);
    *reinterpret_cast<uint4v*>(Dw + ob) = o0;
    *reinterpret_cast<uint4v*>(Dw + ob + 64) = o1;
  }
}

// ---------------- pointwise mix MFMA + BN + SiLU + residual ----------------
__global__ __launch_bounds__(256, 2) void pwmix_kernel(
    const unsigned short* __restrict__ D, const unsigned short* __restrict__ pwPack,
    const float* __restrict__ x, const float* __restrict__ mg,
    const float* __restrict__ mb2, const float* __restrict__ mmu,
    const float* __restrict__ mvv, float* __restrict__ out) {
  __shared__ unsigned int sDt[16384];
  __shared__ float smsc[256], smsh[256];
  const int tid = threadIdx.x;
  const int w = tid >> 6, l = tid & 63;
  const int lq = l & 31, hi = l >> 5;
  const int h = blockIdx.x, b = blockIdx.y;
  if (tid < 256) {
    float inv = mg[tid] * rsqrtf(mvv[tid] + EPSV);
    smsc[tid] = inv;
    smsh[tid] = mb2[tid] - mmu[tid] * inv;
  }
  const size_t dbase = ((size_t)b * 256) * 16384 + (size_t)h * 128;
#pragma unroll
  for (int i = 0; i < 8; ++i) {
    int cp = 64 * (i & 1) + 16 * w + (l >> 2);
    int pg = (l & 3) + 4 * (i >> 1);
    const unsigned short* g0 = D + dbase + (size_t)(cp * 2) * 16384 + pg * 8;
    bf16x8 d0 = ld_frag(g0);
    bf16x8 d1 = ld_frag(g0 + 16384);
#pragma unroll
    for (int j = 0; j < 8; ++j) {
      unsigned int word = ((unsigned int)(unsigned short)d0[j]) |
                          (((unsigned int)(unsigned short)d1[j]) << 16);
      int widx = ((pg * 8 + j) * 128 + cp) ^ (j << 2);
      sDt[widx] = word;
    }
  }
  __syncthreads();

  f32x16 z[2][4];
#pragma unroll
  for (int mti = 0; mti < 2; ++mti)
#pragma unroll
    for (int nt = 0; nt < 4; ++nt)
#pragma unroll
      for (int i = 0; i < 16; ++i) z[mti][nt][i] = 0.f;

#pragma unroll
  for (int ks = 0; ks < 16; ++ks) {
    bf16x8 a0 = ld_frag(pwPack + (size_t)(((w * 2 + 0) * 16 + ks) * 64 + l) * 8);
    bf16x8 a1 = ld_frag(pwPack + (size_t)(((w * 2 + 1) * 16 + ks) * 64 + l) * 8);
    bf16x8 bfr[4];
#pragma unroll
    for (int nt = 0; nt < 4; ++nt) {
      int word = ((nt * 32 + lq) * 128 + 8 * ks + 4 * hi) ^ ((lq & 7) << 2);
      bfr[nt] = *reinterpret_cast<const bf16x8*>(
          reinterpret_cast<const unsigned short*>(sDt) + (size_t)word * 2);
    }
#pragma unroll
    for (int nt = 0; nt < 4; ++nt) {
      z[0][nt] = __builtin_amdgcn_mfma_f32_32x32x16_bf16(a0, bfr[nt], z[0][nt], 0, 0, 0);
      z[1][nt] = __builtin_amdgcn_mfma_f32_32x32x16_bf16(a1, bfr[nt], z[1][nt], 0, 0, 0);
    }
  }

#pragma unroll
  for (int mti = 0; mti < 2; ++mti) {
    int ob = (w * 2 + mti) * 32 + 4 * hi;
#pragma unroll
    for (int r = 0; r < 16; ++r) {
      int o = ob + (r & 3) + 8 * (r >> 2);
      float sc = smsc[o], sh = smsh[o];
#pragma unroll
      for (int nt = 0; nt < 4; ++nt) {
        int px = nt * 32 + lq;
        size_t gi = (((size_t)(b * 256 + o)) << 14) + (size_t)h * 128 + px;
        float val = z[mti][nt][r] * sc + sh;
        out[gi] = x[gi] + silu_f(val);
      }
    }
  }
}

extern "C" void kernel_launch(void* const* d_in, const int* in_sizes, int n_in,
                              void* d_out, int out_size, void* d_ws, size_t ws_size,
                              hipStream_t stream) {
  const float* x     = (const float*)d_in[0];
  const float* wq    = (const float*)d_in[1];
  const float* wk    = (const float*)d_in[2];
  const float* wvp   = (const float*)d_in[3];
  const float* wproj = (const float*)d_in[4];
  const float* bng   = (const float*)d_in[5];
  const float* bnb   = (const float*)d_in[6];
  const float* bnm   = (const float*)d_in[7];
  const float* bnv   = (const float*)d_in[8];
  const float* dww   = (const float*)d_in[9];
  const float* pww   = (const float*)d_in[10];
  const float* mg    = (const float*)d_in[11];
  const float* mb2   = (const float*)d_in[12];
  const float* mmu   = (const float*)d_in[13];
  const float* mvv   = (const float*)d_in[14];
  float* out = (float*)d_out;

  char* base = (char*)d_ws;
  unsigned short* D = (unsigned short*)base;                   // dwconv-phase overlay [0,67M)
  float* xkv = (float*)base;                                   //  8,388,608 B
  unsigned short* Qt  = (unsigned short*)(base + 8388608);     // 16,777,216 B
  unsigned short* Kt  = (unsigned short*)(base + 25165824);    //  1,048,576 B
  unsigned short* Vbf = (unsigned short*)(base + 26214400);    //  2,097,152 B
  unsigned short* wqPack = (unsigned short*)(base + 28311552); //     32,768 B
  float* bnsc = (float*)(base + 67108864);
  float* bnsh = (float*)(base + 67109888);
  unsigned short* wpb    = (unsigned short*)(base + 67110912);
  unsigned short* pwPack = (unsigned short*)(base + 67176448);
  unsigned short* yact   = (unsigned short*)(base + 67307520); // 67,108,864 B
  unsigned short* xbfT   = yact;  // aliases yact: xbfT dead before attn writes yact

  cvtT_kernel<<<dim3(256, 4, 8), 256, 0, stream>>>(x, xbfT);
  pool2_kernel<<<dim3(64, 8), 256, 0, stream>>>(xbfT, xkv);
  prep_all<<<449, 256, 0, stream>>>(wproj, bng, bnb, bnm, bnv, pww, wq, wpb, bnsc, bnsh,
                                    pwPack, wqPack);
  gemm_kv<<<dim3(16, 3, 8), 256, 0, stream>>>(wk, wvp, xkv, Kt, Vbf);
  qgemm_mfma<<<dim3(128, 8), 256, 0, stream>>>(xbfT, wqPack, Qt);
  attn_mfma<<<dim3(1024), 256, 0, stream>>>(Qt, Kt, Vbf, wpb, bnsc, bnsh, yact);
  dwconv_kernel<<<2048, 256, 0, stream>>>(yact, dww, D);
  pwmix_kernel<<<dim3(128, 8), 256, 0, stream>>>(D, pwPack, x, mg, mb2, mmu, mvv, out);
}

// Round 15
// 268.765 us; speedup vs baseline: 1.3085x; 1.0408x over previous
//
#include <hip/hip_runtime.h>
#include <hip/hip_bf16.h>
#include <math.h>

#define EPSV 1e-5f

typedef short bf16x8 __attribute__((ext_vector_type(8)));
typedef float f32x16 __attribute__((ext_vector_type(16)));
typedef unsigned int uint4v __attribute__((ext_vector_type(4)));

__device__ __forceinline__ float silu_f(float v) { return v / (1.0f + __expf(-v)); }

__device__ __forceinline__ unsigned short f2bf(float f) {
  __hip_bfloat16 h = __float2bfloat16(f);
  return __builtin_bit_cast(unsigned short, h);
}

__device__ __forceinline__ float bf2f(unsigned short u) {
  return __builtin_bit_cast(float, (unsigned int)u << 16);
}

// hardware 2^x (VOP1 v_exp_f32)
__device__ __forceinline__ float fexp2(float x) {
  float r;
  asm("v_exp_f32 %0, %1" : "=v"(r) : "v"(x));
  return r;
}

// packed f32x2 -> bf16x2 (low = lo, high = hi)
__device__ __forceinline__ unsigned int cvtpk(float lo, float hi) {
  unsigned int r;
  asm("v_cvt_pk_bf16_f32 %0, %1, %2" : "=v"(r) : "v"(lo), "v"(hi));
  return r;
}

__device__ __forceinline__ bf16x8 ld_frag(const unsigned short* p) {
  return *reinterpret_cast<const bf16x8*>(p);
}

__device__ __forceinline__ void gload16(const unsigned short* g, unsigned short* l) {
  __builtin_amdgcn_global_load_lds((const __attribute__((address_space(1))) void*)g,
                                   (__attribute__((address_space(3))) void*)l, 16, 0, 0);
}

// ---------------- cvt+transpose: x fp32 [b][c][n] -> xbfT bf16 [b][n][c] ----------------
__global__ __launch_bounds__(256) void cvtT_kernel(const float* __restrict__ x,
                                                   unsigned short* __restrict__ xbfT) {
  __shared__ unsigned short sT[64 * 68];
  const int tid = threadIdx.x;
  const int b = blockIdx.z, c0 = blockIdx.y * 64, n0 = blockIdx.x * 64;
  const float* xs = x + ((size_t)(b * 256 + c0) << 14) + n0;
#pragma unroll
  for (int pass = 0; pass < 4; ++pass) {
    int cc = (tid >> 4) + pass * 16;
    int col = (tid & 15) * 4;
    float4 v = *reinterpret_cast<const float4*>(xs + ((size_t)cc << 14) + col);
    unsigned short* d = &sT[cc * 68 + col];
    d[0] = f2bf(v.x); d[1] = f2bf(v.y); d[2] = f2bf(v.z); d[3] = f2bf(v.w);
  }
  __syncthreads();
  int n = tid >> 2, cs = (tid & 3) * 16;
  unsigned short tmp[16];
#pragma unroll
  for (int i = 0; i < 16; ++i) tmp[i] = sT[(cs + i) * 68 + n];
  unsigned short* dst = xbfT + (((size_t)b * 16384 + n0 + n) << 8) + c0 + cs;
  *reinterpret_cast<uint4*>(dst) = *reinterpret_cast<uint4*>(tmp);
  *reinterpret_cast<uint4*>(dst + 8) = *reinterpret_cast<uint4*>(tmp + 8);
}

// ---------------- 4x4 pool from xbfT (bf16 [b][n][c]) -> xkv fp32 [b][c][32][32] -------
__global__ __launch_bounds__(256) void pool2_kernel(const unsigned short* __restrict__ xbfT,
                                                    float* __restrict__ xkv) {
  const int tid = threadIdx.x;
  const int w = tid >> 6, l = tid & 63;
  const int half = blockIdx.x & 1, hh = blockIdx.x >> 1;  // grid (64, 8)
  const int b = blockIdx.y;
  const int c0 = l * 4;
  float acc[4][4] = {};
#pragma unroll
  for (int wwi = 0; wwi < 4; ++wwi) {
    int ww = half * 16 + w * 4 + wwi;
#pragma unroll
    for (int i = 0; i < 4; ++i)
#pragma unroll
      for (int j = 0; j < 4; ++j) {
        int n = (4 * hh + i) * 128 + 4 * ww + j;
        ushort4 v = *reinterpret_cast<const ushort4*>(xbfT + (((size_t)b * 16384 + n) << 8) +
                                                      c0);
        acc[wwi][0] += bf2f(v.x);
        acc[wwi][1] += bf2f(v.y);
        acc[wwi][2] += bf2f(v.z);
        acc[wwi][3] += bf2f(v.w);
      }
  }
#pragma unroll
  for (int cc = 0; cc < 4; ++cc) {
    float4 o = make_float4(acc[0][cc] * 0.0625f, acc[1][cc] * 0.0625f, acc[2][cc] * 0.0625f,
                           acc[3][cc] * 0.0625f);
    float* dst = xkv + (((size_t)(b * 256 + c0 + cc)) << 10) + hh * 32 + half * 16 + w * 4;
    *reinterpret_cast<float4*>(dst) = o;
  }
}

// ---------------- prep (merged): wpb, BN scale/shift, pwPack, wqPack ----------------
__global__ __launch_bounds__(256) void prep_all(const float* __restrict__ wproj,
                                                const float* __restrict__ bng,
                                                const float* __restrict__ bnb,
                                                const float* __restrict__ bnm,
                                                const float* __restrict__ bnv,
                                                const float* __restrict__ pww,
                                                const float* __restrict__ wq,
                                                unsigned short* __restrict__ wpb,
                                                float* __restrict__ bnsc,
                                                float* __restrict__ bnsh,
                                                unsigned short* __restrict__ pwPack,
                                                unsigned short* __restrict__ wqPack) {
  int i = blockIdx.x * 256 + threadIdx.x;
  if (i < 32768) {
    int j = i & 7, lane = (i >> 3) & 63, kc = (i >> 9) & 7, ctcg = i >> 12;
    int row = (ctcg >> 2) * 128 + (ctcg & 3) * 32 + (lane & 31);
    int col = kc * 16 + (lane >> 5) * 8 + j;
    wpb[i] = f2bf(wproj[row * 128 + col]);
  } else if (i < 33024) {
    int c = i - 32768;
    float inv = bng[c] / sqrtf(bnv[c] + EPSV);
    bnsc[c] = inv;
    bnsh[c] = bnb[c] - bnm[c] * inv;
  } else if (i < 98560) {
    int f = i - 33024;
    int j = f & 7, lane = (f >> 3) & 63, ks = (f >> 9) & 15, mt = f >> 13;
    int o = mt * 32 + (lane & 31);
    int cc = ks * 16 + (lane >> 5) * 8 + j;
    pwPack[f] = f2bf(pww[o * 256 + cc]);
  } else if (i < 114944) {
    int g = i - 98560;
    int j = g & 7, lane = (g >> 3) & 63, ks = (g >> 9) & 15, mt = g >> 13;
    int o = mt * 32 + (lane & 31);
    int cc = ks * 16 + (lane >> 5) * 8 + j;
    wqPack[g] = f2bf(wq[o * 256 + cc] * 0.18033688011112042f);  // 0.125*log2(e)
  }
}

// ------- MERGED launch: blocks [0,384) = K+V fp32 GEMM; [384,1408) = Q MFMA GEMM -------
// The two are data-independent (xkv <- pool2, xbfT <- cvtT) and both underfill the chip;
// one launch lets them overlap. Bodies verbatim from the split kernels.
__global__ __launch_bounds__(256, 4) void kvq_fused(
    const float* __restrict__ wk, const float* __restrict__ wv,
    const float* __restrict__ X, unsigned short* __restrict__ Kt,
    unsigned short* __restrict__ Vbf, const unsigned short* __restrict__ xbfT,
    const unsigned short* __restrict__ wqPack, unsigned short* __restrict__ Qt) {
  __shared__ __align__(16) unsigned char smemU[34816];
  const int gbid = blockIdx.x;
  const int tid = threadIdx.x;
  if (gbid < 384) {
    // ----- gemm_kv path: part 0 -> Kt, part 1/2 -> Vbf halves -----
    float* sW = (float*)smemU;             // 64*68 f
    float* sX = (float*)(smemU + 17408);   // 64*68 f
    const int b = gbid / 48, rem = gbid % 48;
    const int part = rem / 16;
    const int n0 = (rem % 16) * 64;
    const int m0 = (part == 0) ? 0 : (part - 1) * 64;
    const float* W = (part == 0) ? wk : wv;
    const size_t xoff = (size_t)b * 256 * 1024;
    const int tm4 = (tid >> 4) * 4, tn4 = (tid & 15) * 4;
    float acc[4][4] = {};
    for (int k0 = 0; k0 < 256; k0 += 64) {
      __syncthreads();
#pragma unroll
      for (int i = 0; i < 16; ++i) {
        int flat = tid + i * 256;
        int kk = flat & 63, mm = flat >> 6;
        sW[kk * 68 + mm] = W[(m0 + mm) * 256 + k0 + kk];
        sX[kk * 68 + mm] = X[xoff + (size_t)(k0 + kk) * 1024 + n0 + mm];
      }
      __syncthreads();
#pragma unroll 8
      for (int k = 0; k < 64; ++k) {
        float4 a4 = *reinterpret_cast<const float4*>(&sW[k * 68 + tm4]);
        float4 b4 = *reinterpret_cast<const float4*>(&sX[k * 68 + tn4]);
        float av[4] = {a4.x, a4.y, a4.z, a4.w};
        float bv[4] = {b4.x, b4.y, b4.z, b4.w};
#pragma unroll
        for (int i = 0; i < 4; ++i)
#pragma unroll
          for (int j = 0; j < 4; ++j) acc[i][j] += av[i] * bv[j];
      }
    }
    if (part == 0) {  // Kt[b][m(1024)][a(64)]
      const size_t coff = (size_t)b * 65536;
#pragma unroll
      for (int j = 0; j < 4; ++j) {
        ushort4 o;
        o.x = f2bf(acc[0][j]); o.y = f2bf(acc[1][j]);
        o.z = f2bf(acc[2][j]); o.w = f2bf(acc[3][j]);
        *reinterpret_cast<ushort4*>(&Kt[coff + (size_t)(n0 + tn4 + j) * 64 + tm4]) = o;
      }
    } else {  // Vbf[b][vc(128)][m(1024)]
      const size_t coff = (size_t)b * 131072;
#pragma unroll
      for (int i = 0; i < 4; ++i) {
        ushort4 o;
        o.x = f2bf(acc[i][0]); o.y = f2bf(acc[i][1]);
        o.z = f2bf(acc[i][2]); o.w = f2bf(acc[i][3]);
        *reinterpret_cast<ushort4*>(&Vbf[coff + (size_t)(m0 + tm4 + i) * 1024 + n0 + tn4]) =
            o;
      }
    }
  } else {
    // ----- qgemm path: Qt[b][n][64a] -----
    unsigned short* sXq = (unsigned short*)smemU;  // [2][128*64]
    const int q = gbid - 384;
    const int w = tid >> 6, l = tid & 63;
    const int lq = l & 31, hi = l >> 5;
    const int b = q >> 7;
    const int n0 = (q & 127) * 128;
    const int lr8 = l >> 3;
    const int gslot = (l & 7) ^ (lr8 & 7);
    const unsigned short* xb = xbfT + (((size_t)b * 16384 + n0) << 8);

#define QSTAGE(buf, ck)                                                       \
  {                                                                           \
    _Pragma("unroll") for (int i = 0; i < 4; ++i) {                           \
      int row = w * 32 + i * 8;                                               \
      gload16(xb + ((size_t)(row + lr8) << 8) + (ck) * 64 + gslot * 8,        \
              &sXq[(buf) * 8192 + row * 64]);                                 \
    }                                                                         \
  }

    f32x16 acc0, acc1;
#pragma unroll
    for (int i = 0; i < 16; ++i) { acc0[i] = 0.f; acc1[i] = 0.f; }

    QSTAGE(0, 0);
    __syncthreads();
    int cur = 0;
    for (int ck = 0; ck < 4; ++ck) {
      if (ck < 3) QSTAGE(cur ^ 1, ck + 1);
      const unsigned short* xl = sXq + cur * 8192;
#pragma unroll
      for (int k2 = 0; k2 < 4; ++k2) {
        bf16x8 bfr = ld_frag(xl + (w * 32 + lq) * 64 + (((2 * k2 + hi) ^ (lq & 7)) << 3));
        int ks = ck * 4 + k2;
        bf16x8 a0 = ld_frag(wqPack + (size_t)((ks)*64 + l) * 8);
        bf16x8 a1 = ld_frag(wqPack + (size_t)((16 + ks) * 64 + l) * 8);
        acc0 = __builtin_amdgcn_mfma_f32_32x32x16_bf16(a0, bfr, acc0, 0, 0, 0);
        acc1 = __builtin_amdgcn_mfma_f32_32x32x16_bf16(a1, bfr, acc1, 0, 0, 0);
      }
      __syncthreads();
      cur ^= 1;
    }
#undef QSTAGE

    unsigned short* so2 = sXq + w * 2304;  // 32*72
#pragma unroll
    for (int r = 0; r < 16; ++r) {
      int a = (r & 3) + 8 * (r >> 2) + 4 * hi;
      so2[lq * 72 + a] = f2bf(acc0[r]);
      so2[lq * 72 + 32 + a] = f2bf(acc1[r]);
    }
#pragma unroll
    for (int pass = 0; pass < 4; ++pass) {
      int flat = pass * 64 + l;
      int row = flat >> 3, col8 = (flat & 7) * 8;
      bf16x8 v = ld_frag(so2 + row * 72 + col8);
      *reinterpret_cast<bf16x8*>(Qt + ((size_t)b * 16384 + n0 + w * 32 + row) * 64 + col8) =
          v;
    }
  }
}

// ---------------- MFMA flash attention + proj + BN + SiLU -> yact bf16 ----------------
// Round-8 exact (do not touch): batch-major grid, syncthreads double-buffer loop,
// static-max base-2 softmax (p = 2^(s-16)), ones-MFMA row-sum, divide epilogue.
__global__ __launch_bounds__(256, 3) void attn_mfma(
    const unsigned short* __restrict__ Qt, const unsigned short* __restrict__ Kt,
    const unsigned short* __restrict__ Vb, const unsigned short* __restrict__ wpb,
    const float* __restrict__ bnsc, const float* __restrict__ bnsh,
    unsigned short* __restrict__ yact) {
  __shared__ __align__(16) unsigned char smem[49152];
  unsigned short* const sK = (unsigned short*)smem;            // [2][64][64]
  unsigned short* const sV = (unsigned short*)(smem + 16384);  // [2][128][64]
  const int tid = threadIdx.x;
  const int w = tid >> 6, l = tid & 63;
  const int lq = l & 31, hi = l >> 5;
  const int bid = blockIdx.x;
  const int b = bid >> 7;
  const int q0 = (bid & 127) * 128 + w * 32;

  const unsigned short* Qp = Qt + ((size_t)b * 16384 + q0 + lq) * 64 + hi * 8;
  bf16x8 qf[4];
#pragma unroll
  for (int kc = 0; kc < 4; ++kc) qf[kc] = ld_frag(Qp + kc * 16);

  const uint4v ow = {0x3F803F80u, 0x3F803F80u, 0x3F803F80u, 0x3F803F80u};
  const bf16x8 onesf = __builtin_bit_cast(bf16x8, ow);

  f32x16 acc[4], accS;
#pragma unroll
  for (int t = 0; t < 4; ++t)
#pragma unroll
    for (int i = 0; i < 16; ++i) acc[t][i] = 0.f;
#pragma unroll
  for (int i = 0; i < 16; ++i) accS[i] = 0.f;

  const unsigned short* Kb = Kt + (size_t)b * 65536;
  const unsigned short* Vbb = Vb + (size_t)b * 131072;
  const int lr8 = l >> 3;
  const int gslot = (l & 7) ^ (lr8 & 7);

#define STAGE(buf, ch)                                                           \
  {                                                                              \
    const int m0s = (ch) * 64;                                                   \
    _Pragma("unroll") for (int i = 0; i < 2; ++i) {                              \
      int row8 = w * 16 + i * 8;                                                 \
      gload16(Kb + (size_t)(m0s + row8 + lr8) * 64 + gslot * 8,                  \
              sK + (buf) * 4096 + row8 * 64);                                    \
    }                                                                            \
    _Pragma("unroll") for (int j = 0; j < 4; ++j) {                              \
      int vc8 = w * 32 + j * 8;                                                  \
      gload16(Vbb + (size_t)(vc8 + lr8) * 1024 + m0s + gslot * 8,                \
              sV + (buf) * 8192 + vc8 * 64);                                     \
    }                                                                            \
  }

  STAGE(0, 0);
  __syncthreads();
  int cur = 0;
  for (int ch = 0; ch < 16; ++ch) {
    if (ch < 15) STAGE(cur ^ 1, ch + 1);
    const unsigned short* kb = sK + cur * 4096;
    const unsigned short* vb = sV + cur * 8192;
#pragma unroll
    for (int msi = 0; msi < 2; ++msi) {
      const int ms = msi * 32;
      bf16x8 kf[4];
#pragma unroll
      for (int kc = 0; kc < 4; ++kc)
        kf[kc] = ld_frag(kb + (ms + lq) * 64 + (((2 * kc + hi) ^ (lq & 7)) << 3));
      f32x16 sa;
#pragma unroll
      for (int i = 0; i < 16; ++i) sa[i] = 0.f;
      __builtin_amdgcn_s_setprio(1);
#pragma unroll
      for (int kc = 0; kc < 4; ++kc)
        sa = __builtin_amdgcn_mfma_f32_32x32x16_bf16(kf[kc], qf[kc], sa, 0, 0, 0);
      __builtin_amdgcn_s_setprio(0);

      // p = 2^(s - 16): static shift, exact softmax after final normalization
      float p[16];
#pragma unroll
      for (int r = 0; r < 16; ++r) p[r] = fexp2(sa[r] - 16.0f);

      unsigned int wpk[8];
#pragma unroll
      for (int i = 0; i < 8; ++i) wpk[i] = cvtpk(p[2 * i], p[2 * i + 1]);
      auto s01 = __builtin_amdgcn_permlane32_swap(wpk[0], wpk[2], false, false);
      auto s23 = __builtin_amdgcn_permlane32_swap(wpk[1], wpk[3], false, false);
      auto s45 = __builtin_amdgcn_permlane32_swap(wpk[4], wpk[6], false, false);
      auto s67 = __builtin_amdgcn_permlane32_swap(wpk[5], wpk[7], false, false);
      uint4v f0 = {(unsigned int)s01[0], (unsigned int)s23[0], (unsigned int)s01[1],
                   (unsigned int)s23[1]};
      uint4v f1 = {(unsigned int)s45[0], (unsigned int)s67[0], (unsigned int)s45[1],
                   (unsigned int)s67[1]};
      bf16x8 pf0 = __builtin_bit_cast(bf16x8, f0);
      bf16x8 pf1 = __builtin_bit_cast(bf16x8, f1);

      __builtin_amdgcn_s_setprio(1);
#pragma unroll
      for (int t = 0; t < 4; ++t) {
        bf16x8 vf0 =
            ld_frag(vb + (t * 32 + lq) * 64 + ((((ms >> 3) + hi) ^ (lq & 7)) << 3));
        bf16x8 vf1 =
            ld_frag(vb + (t * 32 + lq) * 64 + ((((ms >> 3) + 2 + hi) ^ (lq & 7)) << 3));
        acc[t] = __builtin_amdgcn_mfma_f32_32x32x16_bf16(pf0, vf0, acc[t], 0, 0, 0);
        acc[t] = __builtin_amdgcn_mfma_f32_32x32x16_bf16(pf1, vf1, acc[t], 0, 0, 0);
      }
      accS = __builtin_amdgcn_mfma_f32_32x32x16_bf16(pf0, onesf, accS, 0, 0, 0);
      accS = __builtin_amdgcn_mfma_f32_32x32x16_bf16(pf1, onesf, accS, 0, 0, 0);
      __builtin_amdgcn_s_setprio(0);
    }
    __syncthreads();
    cur ^= 1;
  }
#undef STAGE

  unsigned short* so = (unsigned short*)smem + w * 4096;
#pragma unroll
  for (int t = 0; t < 4; ++t)
#pragma unroll
    for (int r = 0; r < 16; ++r) {
      int q = (r & 3) + 8 * (r >> 2) + 4 * hi;
      int col = t * 32 + lq;
      so[q * 128 + (col ^ ((q & 15) << 3))] = f2bf(acc[t][r] / accS[r]);
    }
  __syncthreads();

  bf16x8 of[8];
#pragma unroll
  for (int kc = 0; kc < 8; ++kc) {
    int colr = kc * 16 + hi * 8;
    of[kc] = ld_frag(&so[lq * 128 + (colr ^ ((lq & 15) << 3))]);
  }
#pragma unroll
  for (int cg = 0; cg < 2; ++cg) {
    f32x16 z[4];
#pragma unroll
    for (int t = 0; t < 4; ++t)
#pragma unroll
      for (int i = 0; i < 16; ++i) z[t][i] = 0.f;
#pragma unroll
    for (int ct = 0; ct < 4; ++ct) {
      const unsigned short* wp = wpb + (size_t)(cg * 4 + ct) * 4096 + (size_t)l * 8;
#pragma unroll
      for (int kc = 0; kc < 8; ++kc) {
        bf16x8 wf = ld_frag(wp + kc * 512);
        z[ct] = __builtin_amdgcn_mfma_f32_32x32x16_bf16(wf, of[kc], z[ct], 0, 0, 0);
      }
    }
#pragma unroll
    for (int ct = 0; ct < 4; ++ct)
#pragma unroll
      for (int r = 0; r < 16; ++r) {
        int c = cg * 128 + ct * 32 + (r & 3) + 8 * (r >> 2) + 4 * hi;
        float val = z[ct][r] * bnsc[c] + bnsh[c];
        yact[((size_t)(b * 256 + c)) * 16384 + q0 + lq] = f2bf(silu_f(val));
      }
  }
}

// ---------------- depthwise 3x3: yact bf16 -> D bf16, one (b,c) plane per block --------
__global__ __launch_bounds__(256, 4) void dwconv_kernel(const unsigned short* __restrict__ yact,
                                                        const float* __restrict__ dww,
                                                        unsigned short* __restrict__ D) {
  __shared__ unsigned int sP[130 * 67];
  const int tid = threadIdx.x;
  const int bc = blockIdx.x;
  const int c = bc & 255;
  for (int s = tid; s < 130 * 67; s += 256) sP[s] = 0;
  __syncthreads();
  const unsigned int* ysrc = reinterpret_cast<const unsigned int*>(yact) + (size_t)bc * 8192;
#pragma unroll
  for (int i = 0; i < 8; ++i) {
    int wi4 = tid + 256 * i;
    uint4 v = *reinterpret_cast<const uint4*>(ysrc + (size_t)wi4 * 4);
    int row = wi4 >> 4;
    int cw = (wi4 & 15) * 4;
    unsigned int* dst = &sP[(row + 1) * 67 + 1 + cw];
    dst[0] = v.x; dst[1] = v.y; dst[2] = v.z; dst[3] = v.w;
  }
  __syncthreads();
  float w9[9];
#pragma unroll
  for (int k = 0; k < 9; ++k) w9[k] = dww[c * 9 + k];
#pragma unroll
  for (int it = 0; it < 4; ++it) {
    int u = tid + 256 * it;
    int rho = u >> 4;
    int wg = u & 15;
    float a0[8] = {}, a1[8] = {};
#pragma unroll
    for (int ir = 0; ir < 4; ++ir) {
      int srow = rho * 2 + ir;
      const unsigned int* rp = &sP[srow * 67 + 4 * wg];
      float f[12];
#pragma unroll
      for (int k = 0; k < 6; ++k) {
        unsigned int wv = rp[k];
        f[2 * k] = __builtin_bit_cast(float, wv << 16);
        f[2 * k + 1] = __builtin_bit_cast(float, wv & 0xffff0000u);
      }
      if (ir < 3) {
#pragma unroll
        for (int cc = 0; cc < 8; ++cc)
#pragma unroll
          for (int dc = 0; dc < 3; ++dc) a0[cc] += f[cc + 1 + dc] * w9[ir * 3 + dc];
      }
      if (ir > 0) {
#pragma unroll
        for (int cc = 0; cc < 8; ++cc)
#pragma unroll
          for (int dc = 0; dc < 3; ++dc) a1[cc] += f[cc + 1 + dc] * w9[(ir - 1) * 3 + dc];
      }
    }
    uint4v o0, o1;
#pragma unroll
    for (int k = 0; k < 4; ++k) {
      o0[k] = (unsigned int)f2bf(a0[2 * k]) | ((unsigned int)f2bf(a0[2 * k + 1]) << 16);
      o1[k] = (unsigned int)f2bf(a1[2 * k]) | ((unsigned int)f2bf(a1[2 * k + 1]) << 16);
    }
    size_t ob = (size_t)bc * 8192 + (size_t)(rho * 2) * 64 + wg * 4;
    unsigned int* Dw = reinterpret_cast<unsigned int*>(D);
    *reinterpret_cast<uint4v*>(Dw + ob) = o0;
    *reinterpret_cast<uint4v*>(Dw + ob + 64) = o1;
  }
}

// ---------------- pointwise mix MFMA + BN + SiLU + residual ----------------
__global__ __launch_bounds__(256, 2) void pwmix_kernel(
    const unsigned short* __restrict__ D, const unsigned short* __restrict__ pwPack,
    const float* __restrict__ x, const float* __restrict__ mg,
    const float* __restrict__ mb2, const float* __restrict__ mmu,
    const float* __restrict__ mvv, float* __restrict__ out) {
  __shared__ unsigned int sDt[16384];
  __shared__ float smsc[256], smsh[256];
  const int tid = threadIdx.x;
  const int w = tid >> 6, l = tid & 63;
  const int lq = l & 31, hi = l >> 5;
  const int h = blockIdx.x, b = blockIdx.y;
  if (tid < 256) {
    float inv = mg[tid] * rsqrtf(mvv[tid] + EPSV);
    smsc[tid] = inv;
    smsh[tid] = mb2[tid] - mmu[tid] * inv;
  }
  const size_t dbase = ((size_t)b * 256) * 16384 + (size_t)h * 128;
#pragma unroll
  for (int i = 0; i < 8; ++i) {
    int cp = 64 * (i & 1) + 16 * w + (l >> 2);
    int pg = (l & 3) + 4 * (i >> 1);
    const unsigned short* g0 = D + dbase + (size_t)(cp * 2) * 16384 + pg * 8;
    bf16x8 d0 = ld_frag(g0);
    bf16x8 d1 = ld_frag(g0 + 16384);
#pragma unroll
    for (int j = 0; j < 8; ++j) {
      unsigned int word = ((unsigned int)(unsigned short)d0[j]) |
                          (((unsigned int)(unsigned short)d1[j]) << 16);
      int widx = ((pg * 8 + j) * 128 + cp) ^ (j << 2);
      sDt[widx] = word;
    }
  }
  __syncthreads();

  f32x16 z[2][4];
#pragma unroll
  for (int mti = 0; mti < 2; ++mti)
#pragma unroll
    for (int nt = 0; nt < 4; ++nt)
#pragma unroll
      for (int i = 0; i < 16; ++i) z[mti][nt][i] = 0.f;

#pragma unroll
  for (int ks = 0; ks < 16; ++ks) {
    bf16x8 a0 = ld_frag(pwPack + (size_t)(((w * 2 + 0) * 16 + ks) * 64 + l) * 8);
    bf16x8 a1 = ld_frag(pwPack + (size_t)(((w * 2 + 1) * 16 + ks) * 64 + l) * 8);
    bf16x8 bfr[4];
#pragma unroll
    for (int nt = 0; nt < 4; ++nt) {
      int word = ((nt * 32 + lq) * 128 + 8 * ks + 4 * hi) ^ ((lq & 7) << 2);
      bfr[nt] = *reinterpret_cast<const bf16x8*>(
          reinterpret_cast<const unsigned short*>(sDt) + (size_t)word * 2);
    }
#pragma unroll
    for (int nt = 0; nt < 4; ++nt) {
      z[0][nt] = __builtin_amdgcn_mfma_f32_32x32x16_bf16(a0, bfr[nt], z[0][nt], 0, 0, 0);
      z[1][nt] = __builtin_amdgcn_mfma_f32_32x32x16_bf16(a1, bfr[nt], z[1][nt], 0, 0, 0);
    }
  }

#pragma unroll
  for (int mti = 0; mti < 2; ++mti) {
    int ob = (w * 2 + mti) * 32 + 4 * hi;
#pragma unroll
    for (int r = 0; r < 16; ++r) {
      int o = ob + (r & 3) + 8 * (r >> 2);
      float sc = smsc[o], sh = smsh[o];
#pragma unroll
      for (int nt = 0; nt < 4; ++nt) {
        int px = nt * 32 + lq;
        size_t gi = (((size_t)(b * 256 + o)) << 14) + (size_t)h * 128 + px;
        float val = z[mti][nt][r] * sc + sh;
        out[gi] = x[gi] + silu_f(val);
      }
    }
  }
}

extern "C" void kernel_launch(void* const* d_in, const int* in_sizes, int n_in,
                              void* d_out, int out_size, void* d_ws, size_t ws_size,
                              hipStream_t stream) {
  const float* x     = (const float*)d_in[0];
  const float* wq    = (const float*)d_in[1];
  const float* wk    = (const float*)d_in[2];
  const float* wvp   = (const float*)d_in[3];
  const float* wproj = (const float*)d_in[4];
  const float* bng   = (const float*)d_in[5];
  const float* bnb   = (const float*)d_in[6];
  const float* bnm   = (const float*)d_in[7];
  const float* bnv   = (const float*)d_in[8];
  const float* dww   = (const float*)d_in[9];
  const float* pww   = (const float*)d_in[10];
  const float* mg    = (const float*)d_in[11];
  const float* mb2   = (const float*)d_in[12];
  const float* mmu   = (const float*)d_in[13];
  const float* mvv   = (const float*)d_in[14];
  float* out = (float*)d_out;

  char* base = (char*)d_ws;
  unsigned short* D = (unsigned short*)base;                   // dwconv-phase overlay [0,67M)
  float* xkv = (float*)base;                                   //  8,388,608 B
  unsigned short* Qt  = (unsigned short*)(base + 8388608);     // 16,777,216 B
  unsigned short* Kt  = (unsigned short*)(base + 25165824);    //  1,048,576 B
  unsigned short* Vbf = (unsigned short*)(base + 26214400);    //  2,097,152 B
  unsigned short* wqPack = (unsigned short*)(base + 28311552); //     32,768 B
  float* bnsc = (float*)(base + 67108864);
  float* bnsh = (float*)(base + 67109888);
  unsigned short* wpb    = (unsigned short*)(base + 67110912);
  unsigned short* pwPack = (unsigned short*)(base + 67176448);
  unsigned short* yact   = (unsigned short*)(base + 67307520); // 67,108,864 B
  unsigned short* xbfT   = yact;  // aliases yact: xbfT dead before attn writes yact

  cvtT_kernel<<<dim3(256, 4, 8), 256, 0, stream>>>(x, xbfT);
  pool2_kernel<<<dim3(64, 8), 256, 0, stream>>>(xbfT, xkv);
  prep_all<<<449, 256, 0, stream>>>(wproj, bng, bnb, bnm, bnv, pww, wq, wpb, bnsc, bnsh,
                                    pwPack, wqPack);
  kvq_fused<<<1408, 256, 0, stream>>>(wk, wvp, xkv, Kt, Vbf, xbfT, wqPack, Qt);
  attn_mfma<<<dim3(1024), 256, 0, stream>>>(Qt, Kt, Vbf, wpb, bnsc, bnsh, yact);
  dwconv_kernel<<<2048, 256, 0, stream>>>(yact, dww, D);
  pwmix_kernel<<<dim3(128, 8), 256, 0, stream>>>(D, pwPack, x, mg, mb2, mmu, mvv, out);
}